// Round 1
// baseline (255.281 us; speedup 1.0000x reference)
//
#include <hip/hip_runtime.h>
#include <math.h>

// SoftMoE fp32: B=4,S=4096,D=768,E=16,SLOTS=1,H=3072
constexpr int B = 4, S = 4096, D = 768, E = 16, N = 16, H = 3072;
constexpr int SCH = 64;            // s-chunk length for xs partials
constexpr int NSCH = S / SCH;      // 64 chunks
constexpr int DQ = 4;              // d-split in ffn1
constexpr int HQ = 8;              // h-split in ffn2

// workspace layout (float offsets)
constexpr size_t OFF_PHIT = 0;                                   // N*D
constexpr size_t OFF_LOG  = OFF_PHIT + (size_t)N * D;            // B*S*N
constexpr size_t OFF_DW   = OFF_LOG + (size_t)B * S * N;         // B*S*N
constexpr size_t OFF_CMAX = OFF_DW + (size_t)B * S * N;          // B*N
constexpr size_t OFF_CSUM = OFF_CMAX + (size_t)B * N;            // B*N
constexpr size_t OFF_XSP  = OFF_CSUM + (size_t)B * N;            // B*NSCH*N*D
constexpr size_t OFF_XS   = OFF_XSP + (size_t)B * NSCH * N * D;  // B*N*D
constexpr size_t OFF_HP   = OFF_XS + (size_t)B * N * D;          // DQ*B*E*H
constexpr size_t OFF_HACT = OFF_HP + (size_t)DQ * B * E * H;     // B*E*H
constexpr size_t OFF_YSP  = OFF_HACT + (size_t)B * E * H;        // HQ*B*E*D
constexpr size_t OFF_YS   = OFF_YSP + (size_t)HQ * B * E * D;    // B*E*D

// ---------------- K0: phi [D][N] -> phi_t [N][D] ----------------
__global__ __launch_bounds__(256) void k_phit(const float* __restrict__ phi,
                                              float* __restrict__ phit) {
    int i = blockIdx.x * 256 + threadIdx.x;   // i over N*D, n-major output
    int n = i / D, d = i % D;
    phit[i] = phi[(size_t)d * N + n];
}

// ---------------- K1: logits + dispatch softmax ----------------
// grid: B*(S/16) = 1024, block 256. thread = (s_local = t>>4, n = t&15)
__global__ __launch_bounds__(256) void k_logits(const float* __restrict__ x,
                                                const float* __restrict__ phit,
                                                float* __restrict__ logits,
                                                float* __restrict__ dw) {
    const int t = threadIdx.x;
    const int blk = blockIdx.x;
    const int b = blk / (S / 16);
    const int sc = blk % (S / 16);
    const int sl = t >> 4;
    const int n = t & 15;
    const int s = sc * 16 + sl;
    const float* xrow = x + ((size_t)b * S + s) * D;
    const float* ph = phit + (size_t)n * D;
    float acc = 0.f;
#pragma unroll 4
    for (int d = 0; d < D; d += 4) {
        const float4 xv = *reinterpret_cast<const float4*>(xrow + d);
        const float4 pv = *reinterpret_cast<const float4*>(ph + d);
        acc = fmaf(xv.x, pv.x, acc);
        acc = fmaf(xv.y, pv.y, acc);
        acc = fmaf(xv.z, pv.z, acc);
        acc = fmaf(xv.w, pv.w, acc);
    }
    __shared__ float l_lds[16][16];
    l_lds[sl][n] = acc;
    __syncthreads();
    float m = -1e30f;
#pragma unroll
    for (int j = 0; j < 16; ++j) m = fmaxf(m, l_lds[sl][j]);
    float sum = 0.f;
#pragma unroll
    for (int j = 0; j < 16; ++j) sum += __expf(l_lds[sl][j] - m);
    const float w = __expf(acc - m) / sum;
    const size_t o = ((size_t)b * S + s) * N + n;
    logits[o] = acc;
    dw[o] = w;
}

// ---------------- K2: combine softmax stats over S ----------------
// grid: B*N = 64 blocks, block 256
__global__ __launch_bounds__(256) void k_cstats(const float* __restrict__ logits,
                                                float* __restrict__ cmax,
                                                float* __restrict__ csum) {
    const int bn = blockIdx.x;
    const int b = bn / N, n = bn % N;
    const int t = threadIdx.x;
    const float* base = logits + (size_t)b * S * N + n;
    float vals[16];
    float m = -1e30f;
#pragma unroll
    for (int k = 0; k < 16; ++k) {
        vals[k] = base[(size_t)(t + k * 256) * N];
        m = fmaxf(m, vals[k]);
    }
    __shared__ float red[256];
    red[t] = m;
    __syncthreads();
    for (int off = 128; off > 0; off >>= 1) {
        if (t < off) red[t] = fmaxf(red[t], red[t + off]);
        __syncthreads();
    }
    const float gm = red[0];
    __syncthreads();
    float sum = 0.f;
#pragma unroll
    for (int k = 0; k < 16; ++k) sum += __expf(vals[k] - gm);
    red[t] = sum;
    __syncthreads();
    for (int off = 128; off > 0; off >>= 1) {
        if (t < off) red[t] += red[t + off];
        __syncthreads();
    }
    if (t == 0) {
        cmax[bn] = gm;
        csum[bn] = red[0];
    }
}

// ---------------- K3: xs partials ----------------
// grid: B*NSCH = 256 blocks, block 192 (thread owns 4 d via float4)
__global__ __launch_bounds__(192) void k_xsp(const float* __restrict__ x,
                                             const float* __restrict__ dw,
                                             float* __restrict__ xsp) {
    const int blk = blockIdx.x;
    const int b = blk / NSCH;
    const int c = blk % NSCH;
    const int t = threadIdx.x;
    const int d = t * 4;
    float ax[16], ay[16], az[16], aw[16];
#pragma unroll
    for (int n = 0; n < 16; ++n) { ax[n] = ay[n] = az[n] = aw[n] = 0.f; }
    const float* xb = x + ((size_t)b * S + (size_t)c * SCH) * D + d;
    const float* dwb = dw + ((size_t)b * S + (size_t)c * SCH) * N;
#pragma unroll 2
    for (int s = 0; s < SCH; ++s) {
        const float4 xv = *reinterpret_cast<const float4*>(xb + (size_t)s * D);
#pragma unroll
        for (int n = 0; n < 16; ++n) {
            const float w = dwb[s * N + n];
            ax[n] = fmaf(w, xv.x, ax[n]);
            ay[n] = fmaf(w, xv.y, ay[n]);
            az[n] = fmaf(w, xv.z, az[n]);
            aw[n] = fmaf(w, xv.w, aw[n]);
        }
    }
    float* o = xsp + ((size_t)b * NSCH + c) * N * D + d;
#pragma unroll
    for (int n = 0; n < 16; ++n) {
        float4 v;
        v.x = ax[n]; v.y = ay[n]; v.z = az[n]; v.w = aw[n];
        *reinterpret_cast<float4*>(o + (size_t)n * D) = v;
    }
}

// ---------------- K4: reduce xs partials ----------------
// grid: B*N*D/256 = 192 blocks
__global__ __launch_bounds__(256) void k_xsred(const float* __restrict__ xsp,
                                               float* __restrict__ xs) {
    const int i = blockIdx.x * 256 + threadIdx.x;   // over B*N*D
    const int b = i / (N * D);
    const int rem = i % (N * D);
    const float* p = xsp + (size_t)b * NSCH * N * D + rem;
    float sum = 0.f;
#pragma unroll 4
    for (int c = 0; c < NSCH; ++c) sum += p[(size_t)c * N * D];
    xs[i] = sum;
}

// ---------------- K5: FFN1 partial (h = xs @ W1) ----------------
// grid: E * (H/256) * DQ = 16*12*4 = 768 blocks, block 256
__global__ __launch_bounds__(256) void k_ffn1(const float* __restrict__ xs,
                                              const float* __restrict__ W1,
                                              float* __restrict__ hp) {
    const int blk = blockIdx.x;
    const int dq = blk & 3;
    const int hc = (blk >> 2) % (H / 256);
    const int e = blk / (4 * (H / 256));
    const int t = threadIdx.x;
    const int h = hc * 256 + t;
    constexpr int DL = D / DQ;  // 192
    const float* w = W1 + ((size_t)e * D + (size_t)dq * DL) * H + h;
    const float* xsb = xs + (size_t)e * D + (size_t)dq * DL;  // xs[b][e][d], n==e
    float a0 = 0.f, a1 = 0.f, a2 = 0.f, a3 = 0.f;
#pragma unroll 8
    for (int d = 0; d < DL; ++d) {
        const float wv = w[(size_t)d * H];
        a0 = fmaf(xsb[d], wv, a0);
        a1 = fmaf(xsb[(size_t)N * D + d], wv, a1);
        a2 = fmaf(xsb[(size_t)2 * N * D + d], wv, a2);
        a3 = fmaf(xsb[(size_t)3 * N * D + d], wv, a3);
    }
    const size_t eh = (size_t)e * H + h;
    float* o = hp + (size_t)dq * B * E * H;
    o[eh] = a0;
    o[(size_t)1 * E * H + eh] = a1;
    o[(size_t)2 * E * H + eh] = a2;
    o[(size_t)3 * E * H + eh] = a3;
}

// ---------------- K6: reduce + bias + exact GELU ----------------
// grid: B*E*H/256 = 768 blocks
__global__ __launch_bounds__(256) void k_gelu(const float* __restrict__ hp,
                                              const float* __restrict__ b1,
                                              float* __restrict__ hact) {
    const int i = blockIdx.x * 256 + threadIdx.x;   // over B*E*H
    const int rem = i % (E * H);
    float v = b1[rem];
#pragma unroll
    for (int dq = 0; dq < DQ; ++dq) v += hp[(size_t)dq * B * E * H + i];
    hact[i] = 0.5f * v * (1.0f + erff(v * 0.70710678118654752f));
}

// ---------------- K7: FFN2 partial (ys = h @ W2) ----------------
// grid: E * (D/256) * HQ = 16*3*8 = 384 blocks, block 256
__global__ __launch_bounds__(256) void k_ffn2(const float* __restrict__ hact,
                                              const float* __restrict__ W2,
                                              float* __restrict__ ysp) {
    const int blk = blockIdx.x;
    const int hq = blk & 7;
    const int dc = (blk >> 3) % (D / 256);
    const int e = blk / (8 * (D / 256));
    const int t = threadIdx.x;
    const int d = dc * 256 + t;
    constexpr int HL = H / HQ;  // 384
    const float* w = W2 + ((size_t)e * H + (size_t)hq * HL) * D + d;
    const float* hb = hact + (size_t)e * H + (size_t)hq * HL;
    float a0 = 0.f, a1 = 0.f, a2 = 0.f, a3 = 0.f;
#pragma unroll 8
    for (int k = 0; k < HL; ++k) {
        const float wv = w[(size_t)k * D];
        a0 = fmaf(hb[k], wv, a0);
        a1 = fmaf(hb[(size_t)E * H + k], wv, a1);
        a2 = fmaf(hb[(size_t)2 * E * H + k], wv, a2);
        a3 = fmaf(hb[(size_t)3 * E * H + k], wv, a3);
    }
    const size_t ed = (size_t)e * D + d;
    float* o = ysp + (size_t)hq * B * E * D;
    o[ed] = a0;
    o[(size_t)1 * E * D + ed] = a1;
    o[(size_t)2 * E * D + ed] = a2;
    o[(size_t)3 * E * D + ed] = a3;
}

// ---------------- K8: reduce ys + b2 ----------------
// grid: B*E*D/256 = 192 blocks
__global__ __launch_bounds__(256) void k_ysred(const float* __restrict__ ysp,
                                               const float* __restrict__ b2,
                                               float* __restrict__ ys) {
    const int i = blockIdx.x * 256 + threadIdx.x;   // over B*E*D
    const int rem = i % (E * D);
    float sum = b2[rem];
#pragma unroll
    for (int hq = 0; hq < HQ; ++hq) sum += ysp[(size_t)hq * B * E * D + i];
    ys[i] = sum;
}

// ---------------- K9: combine ----------------
// grid: B*S = 16384 blocks, block 192 (thread owns 4 d)
__global__ __launch_bounds__(192) void k_combine(const float* __restrict__ logits,
                                                 const float* __restrict__ cmax,
                                                 const float* __restrict__ csum,
                                                 const float* __restrict__ ys,
                                                 float* __restrict__ y) {
    const int bs = blockIdx.x;
    const int b = bs / S;
    const int t = threadIdx.x;
    const float* lrow = logits + (size_t)bs * N;
    float cw[16];
#pragma unroll
    for (int n = 0; n < 16; ++n)
        cw[n] = __expf(lrow[n] - cmax[b * N + n]) * (1.0f / csum[b * N + n]) ;
    const float* ysb = ys + (size_t)b * E * D + t * 4;
    float axx = 0.f, ayy = 0.f, azz = 0.f, aww = 0.f;
#pragma unroll
    for (int n = 0; n < 16; ++n) {
        const float4 v = *reinterpret_cast<const float4*>(ysb + (size_t)n * D);
        axx = fmaf(cw[n], v.x, axx);
        ayy = fmaf(cw[n], v.y, ayy);
        azz = fmaf(cw[n], v.z, azz);
        aww = fmaf(cw[n], v.w, aww);
    }
    float4 out;
    out.x = axx; out.y = ayy; out.z = azz; out.w = aww;
    *reinterpret_cast<float4*>(y + (size_t)bs * D + t * 4) = out;
}

extern "C" void kernel_launch(void* const* d_in, const int* in_sizes, int n_in,
                              void* d_out, int out_size, void* d_ws, size_t ws_size,
                              hipStream_t stream) {
    const float* x   = (const float*)d_in[0];
    const float* phi = (const float*)d_in[1];
    const float* W1  = (const float*)d_in[2];
    const float* b1  = (const float*)d_in[3];
    const float* W2  = (const float*)d_in[4];
    const float* b2  = (const float*)d_in[5];
    float* y = (float*)d_out;
    float* ws = (float*)d_ws;

    float* phit   = ws + OFF_PHIT;
    float* logits = ws + OFF_LOG;
    float* dw     = ws + OFF_DW;
    float* cmax   = ws + OFF_CMAX;
    float* csum   = ws + OFF_CSUM;
    float* xsp    = ws + OFF_XSP;
    float* xs     = ws + OFF_XS;
    float* hp     = ws + OFF_HP;
    float* hact   = ws + OFF_HACT;
    float* ysp    = ws + OFF_YSP;
    float* ys     = ws + OFF_YS;

    k_phit<<<(N * D) / 256, 256, 0, stream>>>(phi, phit);
    k_logits<<<B * (S / 16), 256, 0, stream>>>(x, phit, logits, dw);
    k_cstats<<<B * N, 256, 0, stream>>>(logits, cmax, csum);
    k_xsp<<<B * NSCH, 192, 0, stream>>>(x, dw, xsp);
    k_xsred<<<(B * N * D) / 256, 256, 0, stream>>>(xsp, xs);
    k_ffn1<<<E * (H / 256) * DQ, 256, 0, stream>>>(xs, W1, hp);
    k_gelu<<<(B * E * H) / 256, 256, 0, stream>>>(hp, b1, hact);
    k_ffn2<<<E * (D / 256) * HQ, 256, 0, stream>>>(hact, W2, ysp);
    k_ysred<<<(B * E * D) / 256, 256, 0, stream>>>(ysp, b2, ys);
    k_combine<<<B * S, 192, 0, stream>>>(logits, cmax, csum, ys, y);
}

// Round 2
// 184.795 us; speedup vs baseline: 1.3814x; 1.3814x over previous
//
#include <hip/hip_runtime.h>
#include <math.h>

// SoftMoE fp32: B=4,S=4096,D=768,E=16,SLOTS=1,H=3072
constexpr int B = 4, S = 4096, D = 768, E = 16, N = 16, H = 3072;
constexpr int SCH = 64;            // s-chunk length for xs partials
constexpr int NSCH = S / SCH;      // 64 chunks
constexpr int DQ = 4;              // d-split in ffn1
constexpr int HQ = 8;              // h-split in ffn2

// workspace layout (float offsets)
constexpr size_t OFF_LOG  = 0;                                   // B*S*N
constexpr size_t OFF_DW   = OFF_LOG + (size_t)B * S * N;         // B*S*N
constexpr size_t OFF_CMAX = OFF_DW + (size_t)B * S * N;          // B*N
constexpr size_t OFF_CSUM = OFF_CMAX + (size_t)B * N;            // B*N
constexpr size_t OFF_XSP  = OFF_CSUM + (size_t)B * N;            // B*NSCH*N*D
constexpr size_t OFF_XS   = OFF_XSP + (size_t)B * NSCH * N * D;  // B*N*D
constexpr size_t OFF_HP   = OFF_XS + (size_t)B * N * D;          // DQ*B*E*H
constexpr size_t OFF_HACT = OFF_HP + (size_t)DQ * B * E * H;     // B*E*H
constexpr size_t OFF_YSP  = OFF_HACT + (size_t)B * E * H;        // HQ*B*E*D
constexpr size_t OFF_YS   = OFF_YSP + (size_t)HQ * B * E * D;    // B*E*D

// ---------------- K1: logits + dispatch softmax (phi staged in LDS) ----------------
// grid: B*(S/16) = 1024, block 256. thread = (s_local = t>>4, n = t&15)
__global__ __launch_bounds__(256) void k_logits(const float* __restrict__ x,
                                                const float* __restrict__ phi,
                                                float* __restrict__ logits,
                                                float* __restrict__ dw) {
    __shared__ float ph[16][D + 4];     // padded: n-lane aliasing is 2-way (free)
    __shared__ float l_lds[16][16];
    const int t = threadIdx.x;
    const int blk = blockIdx.x;
    const int b = blk / (S / 16);
    const int sc = blk % (S / 16);

    // stage phi [D][16] -> ph[n][d], transposing. 12288 floats, 12 float4/thread.
#pragma unroll
    for (int i = 0; i < 12; ++i) {
        const int idx = i * 1024 + t * 4;          // element index in phi (d-major)
        const float4 v = *reinterpret_cast<const float4*>(phi + idx);
        const int d0 = idx >> 4;                   // idx / 16
        const int n0 = idx & 15;                   // 4 consecutive n, same d
        ph[n0 + 0][d0] = v.x;
        ph[n0 + 1][d0] = v.y;
        ph[n0 + 2][d0] = v.z;
        ph[n0 + 3][d0] = v.w;
    }
    __syncthreads();

    const int sl = t >> 4;
    const int n = t & 15;
    const int s = sc * 16 + sl;
    const float* xrow = x + ((size_t)b * S + s) * D;
    float acc = 0.f;
#pragma unroll 8
    for (int d = 0; d < D; d += 4) {
        const float4 xv = *reinterpret_cast<const float4*>(xrow + d);
        const float4 pv = *reinterpret_cast<const float4*>(&ph[n][d]);
        acc = fmaf(xv.x, pv.x, acc);
        acc = fmaf(xv.y, pv.y, acc);
        acc = fmaf(xv.z, pv.z, acc);
        acc = fmaf(xv.w, pv.w, acc);
    }
    l_lds[sl][n] = acc;
    __syncthreads();
    float m = -1e30f;
#pragma unroll
    for (int j = 0; j < 16; ++j) m = fmaxf(m, l_lds[sl][j]);
    float sum = 0.f;
#pragma unroll
    for (int j = 0; j < 16; ++j) sum += __expf(l_lds[sl][j] - m);
    const float w = __expf(acc - m) / sum;
    const size_t o = ((size_t)b * S + s) * N + n;
    logits[o] = acc;
    dw[o] = w;
}

// ---------------- K2: combine softmax stats over S ----------------
// grid: B*N = 64 blocks, block 256
__global__ __launch_bounds__(256) void k_cstats(const float* __restrict__ logits,
                                                float* __restrict__ cmax,
                                                float* __restrict__ csum) {
    const int bn = blockIdx.x;
    const int b = bn / N, n = bn % N;
    const int t = threadIdx.x;
    const float* base = logits + (size_t)b * S * N + n;
    float vals[16];
    float m = -1e30f;
#pragma unroll
    for (int k = 0; k < 16; ++k) {
        vals[k] = base[(size_t)(t + k * 256) * N];
        m = fmaxf(m, vals[k]);
    }
    __shared__ float red[256];
    red[t] = m;
    __syncthreads();
    for (int off = 128; off > 0; off >>= 1) {
        if (t < off) red[t] = fmaxf(red[t], red[t + off]);
        __syncthreads();
    }
    const float gm = red[0];
    __syncthreads();
    float sum = 0.f;
#pragma unroll
    for (int k = 0; k < 16; ++k) sum += __expf(vals[k] - gm);
    red[t] = sum;
    __syncthreads();
    for (int off = 128; off > 0; off >>= 1) {
        if (t < off) red[t] += red[t + off];
        __syncthreads();
    }
    if (t == 0) {
        cmax[bn] = gm;
        csum[bn] = red[0];
    }
}

// ---------------- K3: xs partials ----------------
// grid: B*NSCH = 256 blocks, block 192 (thread owns 4 d via float4)
__global__ __launch_bounds__(192) void k_xsp(const float* __restrict__ x,
                                             const float* __restrict__ dw,
                                             float* __restrict__ xsp) {
    const int blk = blockIdx.x;
    const int b = blk / NSCH;
    const int c = blk % NSCH;
    const int t = threadIdx.x;
    const int d = t * 4;
    float ax[16], ay[16], az[16], aw[16];
#pragma unroll
    for (int n = 0; n < 16; ++n) { ax[n] = ay[n] = az[n] = aw[n] = 0.f; }
    const float* xb = x + ((size_t)b * S + (size_t)c * SCH) * D + d;
    const float* dwb = dw + ((size_t)b * S + (size_t)c * SCH) * N;
#pragma unroll 2
    for (int s = 0; s < SCH; ++s) {
        const float4 xv = *reinterpret_cast<const float4*>(xb + (size_t)s * D);
#pragma unroll
        for (int n = 0; n < 16; ++n) {
            const float w = dwb[s * N + n];
            ax[n] = fmaf(w, xv.x, ax[n]);
            ay[n] = fmaf(w, xv.y, ay[n]);
            az[n] = fmaf(w, xv.z, az[n]);
            aw[n] = fmaf(w, xv.w, aw[n]);
        }
    }
    float* o = xsp + ((size_t)b * NSCH + c) * N * D + d;
#pragma unroll
    for (int n = 0; n < 16; ++n) {
        float4 v;
        v.x = ax[n]; v.y = ay[n]; v.z = az[n]; v.w = aw[n];
        *reinterpret_cast<float4*>(o + (size_t)n * D) = v;
    }
}

// ---------------- K4: reduce xs partials ----------------
// grid: B*N*D/256 = 192 blocks
__global__ __launch_bounds__(256) void k_xsred(const float* __restrict__ xsp,
                                               float* __restrict__ xs) {
    const int i = blockIdx.x * 256 + threadIdx.x;   // over B*N*D
    const int b = i / (N * D);
    const int rem = i % (N * D);
    const float* p = xsp + (size_t)b * NSCH * N * D + rem;
    float sum = 0.f;
#pragma unroll 4
    for (int c = 0; c < NSCH; ++c) sum += p[(size_t)c * N * D];
    xs[i] = sum;
}

// ---------------- K5: FFN1 partial (h = xs @ W1) ----------------
// grid: E * (H/256) * DQ = 16*12*4 = 768 blocks, block 256
__global__ __launch_bounds__(256) void k_ffn1(const float* __restrict__ xs,
                                              const float* __restrict__ W1,
                                              float* __restrict__ hp) {
    const int blk = blockIdx.x;
    const int dq = blk & 3;
    const int hc = (blk >> 2) % (H / 256);
    const int e = blk / (4 * (H / 256));
    const int t = threadIdx.x;
    const int h = hc * 256 + t;
    constexpr int DL = D / DQ;  // 192
    const float* w = W1 + ((size_t)e * D + (size_t)dq * DL) * H + h;
    const float* xsb = xs + (size_t)e * D + (size_t)dq * DL;  // xs[b][e][d], n==e
    float a0 = 0.f, a1 = 0.f, a2 = 0.f, a3 = 0.f;
#pragma unroll 8
    for (int d = 0; d < DL; ++d) {
        const float wv = w[(size_t)d * H];
        a0 = fmaf(xsb[d], wv, a0);
        a1 = fmaf(xsb[(size_t)N * D + d], wv, a1);
        a2 = fmaf(xsb[(size_t)2 * N * D + d], wv, a2);
        a3 = fmaf(xsb[(size_t)3 * N * D + d], wv, a3);
    }
    const size_t eh = (size_t)e * H + h;
    float* o = hp + (size_t)dq * B * E * H;
    o[eh] = a0;
    o[(size_t)1 * E * H + eh] = a1;
    o[(size_t)2 * E * H + eh] = a2;
    o[(size_t)3 * E * H + eh] = a3;
}

// ---------------- K6: reduce + bias + exact GELU ----------------
// grid: B*E*H/256 = 768 blocks
__global__ __launch_bounds__(256) void k_gelu(const float* __restrict__ hp,
                                              const float* __restrict__ b1,
                                              float* __restrict__ hact) {
    const int i = blockIdx.x * 256 + threadIdx.x;   // over B*E*H
    const int rem = i % (E * H);
    float v = b1[rem];
#pragma unroll
    for (int dq = 0; dq < DQ; ++dq) v += hp[(size_t)dq * B * E * H + i];
    hact[i] = 0.5f * v * (1.0f + erff(v * 0.70710678118654752f));
}

// ---------------- K7: FFN2 partial (ys = h @ W2) ----------------
// grid: E * (D/256) * HQ = 16*3*8 = 384 blocks, block 256
__global__ __launch_bounds__(256) void k_ffn2(const float* __restrict__ hact,
                                              const float* __restrict__ W2,
                                              float* __restrict__ ysp) {
    const int blk = blockIdx.x;
    const int hq = blk & 7;
    const int dc = (blk >> 3) % (D / 256);
    const int e = blk / (8 * (D / 256));
    const int t = threadIdx.x;
    const int d = dc * 256 + t;
    constexpr int HL = H / HQ;  // 384
    const float* w = W2 + ((size_t)e * H + (size_t)hq * HL) * D + d;
    const float* hb = hact + (size_t)e * H + (size_t)hq * HL;
    float a0 = 0.f, a1 = 0.f, a2 = 0.f, a3 = 0.f;
#pragma unroll 8
    for (int k = 0; k < HL; ++k) {
        const float wv = w[(size_t)k * D];
        a0 = fmaf(hb[k], wv, a0);
        a1 = fmaf(hb[(size_t)E * H + k], wv, a1);
        a2 = fmaf(hb[(size_t)2 * E * H + k], wv, a2);
        a3 = fmaf(hb[(size_t)3 * E * H + k], wv, a3);
    }
    const size_t ed = (size_t)e * D + d;
    float* o = ysp + (size_t)hq * B * E * D;
    o[ed] = a0;
    o[(size_t)1 * E * D + ed] = a1;
    o[(size_t)2 * E * D + ed] = a2;
    o[(size_t)3 * E * D + ed] = a3;
}

// ---------------- K8: reduce ys + b2 ----------------
// grid: B*E*D/256 = 192 blocks
__global__ __launch_bounds__(256) void k_ysred(const float* __restrict__ ysp,
                                               const float* __restrict__ b2,
                                               float* __restrict__ ys) {
    const int i = blockIdx.x * 256 + threadIdx.x;   // over B*E*D
    const int rem = i % (E * D);
    float sum = b2[rem];
#pragma unroll
    for (int hq = 0; hq < HQ; ++hq) sum += ysp[(size_t)hq * B * E * D + i];
    ys[i] = sum;
}

// ---------------- K9: combine ----------------
// grid: B*S = 16384 blocks, block 192 (thread owns 4 d)
__global__ __launch_bounds__(192) void k_combine(const float* __restrict__ logits,
                                                 const float* __restrict__ cmax,
                                                 const float* __restrict__ csum,
                                                 const float* __restrict__ ys,
                                                 float* __restrict__ y) {
    const int bs = blockIdx.x;
    const int b = bs / S;
    const int t = threadIdx.x;
    const float* lrow = logits + (size_t)bs * N;
    float cw[16];
#pragma unroll
    for (int n = 0; n < 16; ++n)
        cw[n] = __expf(lrow[n] - cmax[b * N + n]) * (1.0f / csum[b * N + n]) ;
    const float* ysb = ys + (size_t)b * E * D + t * 4;
    float axx = 0.f, ayy = 0.f, azz = 0.f, aww = 0.f;
#pragma unroll
    for (int n = 0; n < 16; ++n) {
        const float4 v = *reinterpret_cast<const float4*>(ysb + (size_t)n * D);
        axx = fmaf(cw[n], v.x, axx);
        ayy = fmaf(cw[n], v.y, ayy);
        azz = fmaf(cw[n], v.z, azz);
        aww = fmaf(cw[n], v.w, aww);
    }
    float4 out;
    out.x = axx; out.y = ayy; out.z = azz; out.w = aww;
    *reinterpret_cast<float4*>(y + (size_t)bs * D + t * 4) = out;
}

extern "C" void kernel_launch(void* const* d_in, const int* in_sizes, int n_in,
                              void* d_out, int out_size, void* d_ws, size_t ws_size,
                              hipStream_t stream) {
    const float* x   = (const float*)d_in[0];
    const float* phi = (const float*)d_in[1];
    const float* W1  = (const float*)d_in[2];
    const float* b1  = (const float*)d_in[3];
    const float* W2  = (const float*)d_in[4];
    const float* b2  = (const float*)d_in[5];
    float* y = (float*)d_out;
    float* ws = (float*)d_ws;

    float* logits = ws + OFF_LOG;
    float* dw     = ws + OFF_DW;
    float* cmax   = ws + OFF_CMAX;
    float* csum   = ws + OFF_CSUM;
    float* xsp    = ws + OFF_XSP;
    float* xs     = ws + OFF_XS;
    float* hp     = ws + OFF_HP;
    float* hact   = ws + OFF_HACT;
    float* ysp    = ws + OFF_YSP;
    float* ys     = ws + OFF_YS;

    k_logits<<<B * (S / 16), 256, 0, stream>>>(x, phi, logits, dw);
    k_cstats<<<B * N, 256, 0, stream>>>(logits, cmax, csum);
    k_xsp<<<B * NSCH, 192, 0, stream>>>(x, dw, xsp);
    k_xsred<<<(B * N * D) / 256, 256, 0, stream>>>(xsp, xs);
    k_ffn1<<<E * (H / 256) * DQ, 256, 0, stream>>>(xs, W1, hp);
    k_gelu<<<(B * E * H) / 256, 256, 0, stream>>>(hp, b1, hact);
    k_ffn2<<<E * (D / 256) * HQ, 256, 0, stream>>>(hact, W2, ysp);
    k_ysred<<<(B * E * D) / 256, 256, 0, stream>>>(ysp, b2, ys);
    k_combine<<<B * S, 192, 0, stream>>>(logits, cmax, csum, ys, y);
}

// Round 3
// 184.709 us; speedup vs baseline: 1.3821x; 1.0005x over previous
//
#include <hip/hip_runtime.h>
#include <math.h>

// SoftMoE fp32: B=4,S=4096,D=768,E=16,SLOTS=1,H=3072
constexpr int B = 4, S = 4096, D = 768, E = 16, N = 16, H = 3072;
constexpr int SCH = 64;            // s-chunk length for xs partials
constexpr int NSCH = S / SCH;      // 64 chunks
constexpr int DQ = 16;             // d-split in ffn1 (DL=48)
constexpr int HQ = 48;             // h-split in ffn2 (HL=64)
constexpr int LBLK = 32;           // rows per logits block
constexpr int LPB = S / LBLK;      // logits blocks per b = 128

// workspace layout (float offsets)
constexpr size_t OFF_LOG  = 0;                                   // B*S*N
constexpr size_t OFF_DW   = OFF_LOG + (size_t)B * S * N;         // B*S*N
constexpr size_t OFF_PCM  = OFF_DW + (size_t)B * S * N;          // B*LPB*N
constexpr size_t OFF_PCS  = OFF_PCM + (size_t)B * LPB * N;       // B*LPB*N
constexpr size_t OFF_CMAX = OFF_PCS + (size_t)B * LPB * N;       // B*N
constexpr size_t OFF_CSUM = OFF_CMAX + (size_t)B * N;            // B*N
constexpr size_t OFF_XSP  = OFF_CSUM + (size_t)B * N;            // B*NSCH*N*D
constexpr size_t OFF_XS   = OFF_XSP + (size_t)B * NSCH * N * D;  // B*N*D
constexpr size_t OFF_HP   = OFF_XS + (size_t)B * N * D;          // DQ*B*E*H
constexpr size_t OFF_HACT = OFF_HP + (size_t)DQ * B * E * H;     // B*E*H
constexpr size_t OFF_YSP  = OFF_HACT + (size_t)B * E * H;        // HQ*B*E*D
constexpr size_t OFF_YS   = OFF_YSP + (size_t)HQ * B * E * D;    // B*E*D

// ---------------- K1: logits + dispatch softmax + combine-stats partials ----
// grid: B*LPB = 512 blocks, 256 threads. 16-lane group handles 2 rows.
__global__ __launch_bounds__(256) void k_logits(const float* __restrict__ x,
                                                const float* __restrict__ phi,
                                                float* __restrict__ logits,
                                                float* __restrict__ dw,
                                                float* __restrict__ pcm,
                                                float* __restrict__ pcs) {
    __shared__ float ph[16][D];
    __shared__ float rm[16][16], rs[16][16];
    const int t = threadIdx.x;
    const int blk = blockIdx.x;
    const int b = blk / LPB;
    const int s0 = (blk % LPB) * LBLK;

    // stage phi [D][16] -> ph[n][d], transposing. 12288 floats, 12 float4/thread.
#pragma unroll
    for (int i = 0; i < 12; ++i) {
        const int idx = i * 1024 + t * 4;
        const float4 v = *reinterpret_cast<const float4*>(phi + idx);
        const int d0 = idx >> 4;
        const int n0 = idx & 15;
        ph[n0 + 0][d0] = v.x;
        ph[n0 + 1][d0] = v.y;
        ph[n0 + 2][d0] = v.z;
        ph[n0 + 3][d0] = v.w;
    }
    __syncthreads();

    const int gid = t >> 4;      // group 0..15, owns rows s0+2g, s0+2g+1
    const int ln = t & 15;
    const int s = s0 + gid * 2;
    const float* xr0 = x + ((size_t)b * S + s) * D;
    const float* xr1 = xr0 + D;

    float4 a0[12], a1[12];
#pragma unroll
    for (int j = 0; j < 12; ++j) {
        a0[j] = *reinterpret_cast<const float4*>(xr0 + j * 64 + ln * 4);
        a1[j] = *reinterpret_cast<const float4*>(xr1 + j * 64 + ln * 4);
    }
    float p0[16], p1[16];
#pragma unroll
    for (int n = 0; n < 16; ++n) {
        float q0 = 0.f, q1 = 0.f;
#pragma unroll
        for (int j = 0; j < 12; ++j) {
            const float4 pv = *reinterpret_cast<const float4*>(&ph[n][j * 64 + ln * 4]);
            q0 = fmaf(a0[j].x, pv.x, q0); q1 = fmaf(a1[j].x, pv.x, q1);
            q0 = fmaf(a0[j].y, pv.y, q0); q1 = fmaf(a1[j].y, pv.y, q1);
            q0 = fmaf(a0[j].z, pv.z, q0); q1 = fmaf(a1[j].z, pv.z, q1);
            q0 = fmaf(a0[j].w, pv.w, q0); q1 = fmaf(a1[j].w, pv.w, q1);
        }
        p0[n] = q0; p1[n] = q1;
    }
    // butterfly sum within each 16-lane group -> all lanes get full logits
#pragma unroll
    for (int m = 1; m < 16; m <<= 1) {
#pragma unroll
        for (int n = 0; n < 16; ++n) {
            p0[n] += __shfl_xor(p0[n], m, 64);
            p1[n] += __shfl_xor(p1[n], m, 64);
        }
    }
    // dispatch softmax (over n) for both rows
    float m0 = -1e30f, m1 = -1e30f;
#pragma unroll
    for (int n = 0; n < 16; ++n) { m0 = fmaxf(m0, p0[n]); m1 = fmaxf(m1, p1[n]); }
    float su0 = 0.f, su1 = 0.f;
#pragma unroll
    for (int n = 0; n < 16; ++n) { su0 += __expf(p0[n] - m0); su1 += __expf(p1[n] - m1); }
    const size_t o0 = ((size_t)b * S + s) * N + ln;
    logits[o0] = p0[ln];
    logits[o0 + N] = p1[ln];
    dw[o0] = __expf(p0[ln] - m0) / su0;
    dw[o0 + N] = __expf(p1[ln] - m1) / su1;

    // combine-softmax partial stats: lane ln handles n=ln over its 2 rows
    const float mm = fmaxf(p0[ln], p1[ln]);
    const float ss = __expf(p0[ln] - mm) + __expf(p1[ln] - mm);
    rm[gid][ln] = mm;
    rs[gid][ln] = ss;
    __syncthreads();
    if (t < 16) {  // t = n; merge 16 group-partials (log-sum-exp merge)
        float M = -1e30f;
#pragma unroll
        for (int g = 0; g < 16; ++g) M = fmaxf(M, rm[g][t]);
        float SS = 0.f;
#pragma unroll
        for (int g = 0; g < 16; ++g) SS += rs[g][t] * __expf(rm[g][t] - M);
        pcm[blk * 16 + t] = M;
        pcs[blk * 16 + t] = SS;
    }
}

// ---------------- K2: merge combine-stats partials ----------------
// 1 block, 64 threads: thread = (b,n)
__global__ void k_cmerge(const float* __restrict__ pcm, const float* __restrict__ pcs,
                         float* __restrict__ cmax, float* __restrict__ csum) {
    const int t = threadIdx.x;
    if (t >= 64) return;
    const int b = t >> 4, n = t & 15;
    float M = -1e30f;
#pragma unroll 8
    for (int c = 0; c < LPB; ++c) M = fmaxf(M, pcm[((size_t)b * LPB + c) * 16 + n]);
    float SS = 0.f;
#pragma unroll 8
    for (int c = 0; c < LPB; ++c)
        SS += pcs[((size_t)b * LPB + c) * 16 + n] * __expf(pcm[((size_t)b * LPB + c) * 16 + n] - M);
    cmax[b * 16 + n] = M;
    csum[b * 16 + n] = SS;
}

// ---------------- K3: xs partials ----------------
// grid: B*NSCH = 256 blocks, block 384 (thread owns 2 d via float2)
__global__ __launch_bounds__(384) void k_xsp(const float* __restrict__ x,
                                             const float* __restrict__ dw,
                                             float* __restrict__ xsp) {
    const int blk = blockIdx.x;
    const int b = blk / NSCH;
    const int c = blk % NSCH;
    const int t = threadIdx.x;
    const int d = t * 2;
    float ax[16], ay[16];
#pragma unroll
    for (int n = 0; n < 16; ++n) { ax[n] = 0.f; ay[n] = 0.f; }
    const float* xb = x + ((size_t)b * S + (size_t)c * SCH) * D + d;
    const float* dwb = dw + ((size_t)b * S + (size_t)c * SCH) * N;
#pragma unroll 4
    for (int s = 0; s < SCH; ++s) {
        const float2 xv = *reinterpret_cast<const float2*>(xb + (size_t)s * D);
#pragma unroll
        for (int n = 0; n < 16; ++n) {
            const float w = dwb[s * N + n];
            ax[n] = fmaf(w, xv.x, ax[n]);
            ay[n] = fmaf(w, xv.y, ay[n]);
        }
    }
    float* o = xsp + (size_t)blk * N * D + d;
#pragma unroll
    for (int n = 0; n < 16; ++n) {
        float2 v; v.x = ax[n]; v.y = ay[n];
        *reinterpret_cast<float2*>(o + (size_t)n * D) = v;
    }
}

// ---------------- K4: reduce xs partials ----------------
// grid: B*N*D/256 = 192 blocks
__global__ __launch_bounds__(256) void k_xsred(const float* __restrict__ xsp,
                                               float* __restrict__ xs) {
    const int i = blockIdx.x * 256 + threadIdx.x;   // over B*N*D
    const int b = i / (N * D);
    const int rem = i % (N * D);
    const float* p = xsp + (size_t)b * NSCH * N * D + rem;
    float sum = 0.f;
#pragma unroll 4
    for (int c = 0; c < NSCH; ++c) sum += p[(size_t)c * N * D];
    xs[i] = sum;
}

// ---------------- K5: FFN1 partial (h = xs @ W1), float4 weight loads ------
// grid: E * (H/1024) * DQ = 16*3*16 = 768 blocks, 256 threads, 4 h/thread
__global__ __launch_bounds__(256) void k_ffn1(const float* __restrict__ xs,
                                              const float* __restrict__ W1,
                                              float* __restrict__ hp) {
    const int blk = blockIdx.x;
    const int dq = blk & 15;
    const int hc = (blk >> 4) % 3;
    const int e = blk / 48;
    const int t = threadIdx.x;
    const int h = hc * 1024 + t * 4;
    constexpr int DL = D / DQ;  // 48
    const float* w = W1 + ((size_t)e * D + (size_t)dq * DL) * H + h;
    const float* xsb = xs + (size_t)e * D + (size_t)dq * DL;
    float4 a0{0,0,0,0}, a1{0,0,0,0}, a2{0,0,0,0}, a3{0,0,0,0};
#pragma unroll 4
    for (int d = 0; d < DL; ++d) {
        const float4 wv = *reinterpret_cast<const float4*>(w + (size_t)d * H);
        const float x0 = xsb[d];
        const float x1 = xsb[(size_t)N * D + d];
        const float x2 = xsb[(size_t)2 * N * D + d];
        const float x3 = xsb[(size_t)3 * N * D + d];
        a0.x = fmaf(x0, wv.x, a0.x); a0.y = fmaf(x0, wv.y, a0.y);
        a0.z = fmaf(x0, wv.z, a0.z); a0.w = fmaf(x0, wv.w, a0.w);
        a1.x = fmaf(x1, wv.x, a1.x); a1.y = fmaf(x1, wv.y, a1.y);
        a1.z = fmaf(x1, wv.z, a1.z); a1.w = fmaf(x1, wv.w, a1.w);
        a2.x = fmaf(x2, wv.x, a2.x); a2.y = fmaf(x2, wv.y, a2.y);
        a2.z = fmaf(x2, wv.z, a2.z); a2.w = fmaf(x2, wv.w, a2.w);
        a3.x = fmaf(x3, wv.x, a3.x); a3.y = fmaf(x3, wv.y, a3.y);
        a3.z = fmaf(x3, wv.z, a3.z); a3.w = fmaf(x3, wv.w, a3.w);
    }
    const size_t eh = (size_t)e * H + h;
    float* o = hp + (size_t)dq * B * E * H;
    *reinterpret_cast<float4*>(o + eh) = a0;
    *reinterpret_cast<float4*>(o + (size_t)E * H + eh) = a1;
    *reinterpret_cast<float4*>(o + (size_t)2 * E * H + eh) = a2;
    *reinterpret_cast<float4*>(o + (size_t)3 * E * H + eh) = a3;
}

// ---------------- K6: reduce + bias + exact GELU (float4) ----------------
// grid: B*E*H/4/256 = 192 blocks
__global__ __launch_bounds__(256) void k_gelu(const float* __restrict__ hp,
                                              const float* __restrict__ b1,
                                              float* __restrict__ hact) {
    const int i4 = blockIdx.x * 256 + threadIdx.x;   // over B*E*H/4
    const int rem4 = i4 % (E * H / 4);
    float4 v = *reinterpret_cast<const float4*>(b1 + (size_t)rem4 * 4);
#pragma unroll
    for (int dq = 0; dq < DQ; ++dq) {
        const float4 p = *reinterpret_cast<const float4*>(hp + (size_t)dq * B * E * H + (size_t)i4 * 4);
        v.x += p.x; v.y += p.y; v.z += p.z; v.w += p.w;
    }
    float4 g;
    g.x = 0.5f * v.x * (1.0f + erff(v.x * 0.70710678118654752f));
    g.y = 0.5f * v.y * (1.0f + erff(v.y * 0.70710678118654752f));
    g.z = 0.5f * v.z * (1.0f + erff(v.z * 0.70710678118654752f));
    g.w = 0.5f * v.w * (1.0f + erff(v.w * 0.70710678118654752f));
    *reinterpret_cast<float4*>(hact + (size_t)i4 * 4) = g;
}

// ---------------- K7: FFN2 partial (ys = h @ W2), float4 weight loads ------
// grid: E * HQ = 768 blocks, 192 threads, 4 d/thread
__global__ __launch_bounds__(192) void k_ffn2(const float* __restrict__ hact,
                                              const float* __restrict__ W2,
                                              float* __restrict__ ysp) {
    const int blk = blockIdx.x;
    const int hq = blk % HQ;
    const int e = blk / HQ;
    const int t = threadIdx.x;
    const int d = t * 4;
    constexpr int HL = H / HQ;  // 64
    const float* w = W2 + ((size_t)e * H + (size_t)hq * HL) * D + d;
    const float* hb = hact + (size_t)e * H + (size_t)hq * HL;
    float4 a0{0,0,0,0}, a1{0,0,0,0}, a2{0,0,0,0}, a3{0,0,0,0};
#pragma unroll 4
    for (int k = 0; k < HL; ++k) {
        const float4 wv = *reinterpret_cast<const float4*>(w + (size_t)k * D);
        const float h0 = hb[k];
        const float h1 = hb[(size_t)E * H + k];
        const float h2 = hb[(size_t)2 * E * H + k];
        const float h3 = hb[(size_t)3 * E * H + k];
        a0.x = fmaf(h0, wv.x, a0.x); a0.y = fmaf(h0, wv.y, a0.y);
        a0.z = fmaf(h0, wv.z, a0.z); a0.w = fmaf(h0, wv.w, a0.w);
        a1.x = fmaf(h1, wv.x, a1.x); a1.y = fmaf(h1, wv.y, a1.y);
        a1.z = fmaf(h1, wv.z, a1.z); a1.w = fmaf(h1, wv.w, a1.w);
        a2.x = fmaf(h2, wv.x, a2.x); a2.y = fmaf(h2, wv.y, a2.y);
        a2.z = fmaf(h2, wv.z, a2.z); a2.w = fmaf(h2, wv.w, a2.w);
        a3.x = fmaf(h3, wv.x, a3.x); a3.y = fmaf(h3, wv.y, a3.y);
        a3.z = fmaf(h3, wv.z, a3.z); a3.w = fmaf(h3, wv.w, a3.w);
    }
    const size_t ed = (size_t)e * D + d;
    float* o = ysp + (size_t)hq * B * E * D;
    *reinterpret_cast<float4*>(o + ed) = a0;
    *reinterpret_cast<float4*>(o + (size_t)E * D + ed) = a1;
    *reinterpret_cast<float4*>(o + (size_t)2 * E * D + ed) = a2;
    *reinterpret_cast<float4*>(o + (size_t)3 * E * D + ed) = a3;
}

// ---------------- K8: reduce ys + b2 (float4) ----------------
// grid: B*E*D/4/256 = 48 blocks
__global__ __launch_bounds__(256) void k_ysred(const float* __restrict__ ysp,
                                               const float* __restrict__ b2,
                                               float* __restrict__ ys) {
    const int i4 = blockIdx.x * 256 + threadIdx.x;   // over B*E*D/4
    const int rem4 = i4 % (E * D / 4);
    float4 v = *reinterpret_cast<const float4*>(b2 + (size_t)rem4 * 4);
#pragma unroll
    for (int hq = 0; hq < HQ; ++hq) {
        const float4 p = *reinterpret_cast<const float4*>(ysp + (size_t)hq * B * E * D + (size_t)i4 * 4);
        v.x += p.x; v.y += p.y; v.z += p.z; v.w += p.w;
    }
    *reinterpret_cast<float4*>(ys + (size_t)i4 * 4) = v;
}

// ---------------- K9: combine ----------------
// grid: B*S = 16384 blocks, block 192 (thread owns 4 d)
__global__ __launch_bounds__(192) void k_combine(const float* __restrict__ logits,
                                                 const float* __restrict__ cmax,
                                                 const float* __restrict__ csum,
                                                 const float* __restrict__ ys,
                                                 float* __restrict__ y) {
    const int bs = blockIdx.x;
    const int b = bs / S;
    const int t = threadIdx.x;
    const float* lrow = logits + (size_t)bs * N;
    float cw[16];
#pragma unroll
    for (int n = 0; n < 16; ++n)
        cw[n] = __expf(lrow[n] - cmax[b * N + n]) * (1.0f / csum[b * N + n]);
    const float* ysb = ys + (size_t)b * E * D + t * 4;
    float axx = 0.f, ayy = 0.f, azz = 0.f, aww = 0.f;
#pragma unroll
    for (int n = 0; n < 16; ++n) {
        const float4 v = *reinterpret_cast<const float4*>(ysb + (size_t)n * D);
        axx = fmaf(cw[n], v.x, axx);
        ayy = fmaf(cw[n], v.y, ayy);
        azz = fmaf(cw[n], v.z, azz);
        aww = fmaf(cw[n], v.w, aww);
    }
    float4 out;
    out.x = axx; out.y = ayy; out.z = azz; out.w = aww;
    *reinterpret_cast<float4*>(y + (size_t)bs * D + t * 4) = out;
}

extern "C" void kernel_launch(void* const* d_in, const int* in_sizes, int n_in,
                              void* d_out, int out_size, void* d_ws, size_t ws_size,
                              hipStream_t stream) {
    const float* x   = (const float*)d_in[0];
    const float* phi = (const float*)d_in[1];
    const float* W1  = (const float*)d_in[2];
    const float* b1  = (const float*)d_in[3];
    const float* W2  = (const float*)d_in[4];
    const float* b2  = (const float*)d_in[5];
    float* y = (float*)d_out;
    float* ws = (float*)d_ws;

    float* logits = ws + OFF_LOG;
    float* dw     = ws + OFF_DW;
    float* pcm    = ws + OFF_PCM;
    float* pcs    = ws + OFF_PCS;
    float* cmax   = ws + OFF_CMAX;
    float* csum   = ws + OFF_CSUM;
    float* xsp    = ws + OFF_XSP;
    float* xs     = ws + OFF_XS;
    float* hp     = ws + OFF_HP;
    float* hact   = ws + OFF_HACT;
    float* ysp    = ws + OFF_YSP;
    float* ys     = ws + OFF_YS;

    k_logits<<<B * LPB, 256, 0, stream>>>(x, phi, logits, dw, pcm, pcs);
    k_cmerge<<<1, 64, 0, stream>>>(pcm, pcs, cmax, csum);
    k_xsp<<<B * NSCH, 384, 0, stream>>>(x, dw, xsp);
    k_xsred<<<(B * N * D) / 256, 256, 0, stream>>>(xsp, xs);
    k_ffn1<<<E * 3 * DQ, 256, 0, stream>>>(xs, W1, hp);
    k_gelu<<<(B * E * H / 4) / 256, 256, 0, stream>>>(hp, b1, hact);
    k_ffn2<<<E * HQ, 192, 0, stream>>>(hact, W2, ysp);
    k_ysred<<<(B * E * D / 4) / 256, 256, 0, stream>>>(ysp, b2, ys);
    k_combine<<<B * S, 192, 0, stream>>>(logits, cmax, csum, ys, y);
}

// Round 5
// 152.938 us; speedup vs baseline: 1.6692x; 1.2077x over previous
//
#include <hip/hip_runtime.h>
#include <math.h>

// SoftMoE fp32: B=4,S=4096,D=768,E=16,SLOTS=1,H=3072
constexpr int B = 4, S = 4096, D = 768, E = 16, N = 16, H = 3072;
constexpr int SCH = 32;            // s-chunk length for xs partials
constexpr int NSCH = S / SCH;      // 128 chunks
constexpr int HL = 96;             // h-chunk in fused FFN
constexpr int NHC = H / HL;        // 32
constexpr int LBLK = 32;           // rows per logits block
constexpr int LPB = S / LBLK;      // logits blocks per b = 128

// workspace layout (float offsets)
constexpr size_t OFF_LOG  = 0;                                   // B*S*N
constexpr size_t OFF_DW   = OFF_LOG + (size_t)B * S * N;         // B*S*N
constexpr size_t OFF_PCM  = OFF_DW + (size_t)B * S * N;          // B*LPB*N
constexpr size_t OFF_PCS  = OFF_PCM + (size_t)B * LPB * N;       // B*LPB*N
constexpr size_t OFF_CMAX = OFF_PCS + (size_t)B * LPB * N;       // B*N
constexpr size_t OFF_CSUM = OFF_CMAX + (size_t)B * N;            // B*N
constexpr size_t OFF_XSP  = OFF_CSUM + (size_t)B * N;            // B*NSCH*N*D
constexpr size_t OFF_XS   = OFF_XSP + (size_t)B * NSCH * N * D;  // B*N*D
constexpr size_t OFF_YSP  = OFF_XS + (size_t)B * N * D;          // NHC*B*E*D
constexpr size_t OFF_YS   = OFF_YSP + (size_t)NHC * B * E * D;   // B*E*D

// ---------------- K1: logits + dispatch softmax + combine-stats partials ----
// grid: B*LPB = 512 blocks, 256 threads. 16-lane group handles 2 rows.
__global__ __launch_bounds__(256) void k_logits(const float* __restrict__ x,
                                                const float* __restrict__ phi,
                                                float* __restrict__ logits,
                                                float* __restrict__ dw,
                                                float* __restrict__ pcm,
                                                float* __restrict__ pcs) {
    __shared__ float ph[16][D];
    __shared__ float rm[16][16], rs[16][16];
    const int t = threadIdx.x;
    const int blk = blockIdx.x;
    const int b = blk / LPB;
    const int s0 = (blk % LPB) * LBLK;

#pragma unroll
    for (int i = 0; i < 12; ++i) {
        const int idx = i * 1024 + t * 4;
        const float4 v = *reinterpret_cast<const float4*>(phi + idx);
        const int d0 = idx >> 4;
        const int n0 = idx & 15;
        ph[n0 + 0][d0] = v.x;
        ph[n0 + 1][d0] = v.y;
        ph[n0 + 2][d0] = v.z;
        ph[n0 + 3][d0] = v.w;
    }
    __syncthreads();

    const int gid = t >> 4;
    const int ln = t & 15;
    const int s = s0 + gid * 2;
    const float* xr0 = x + ((size_t)b * S + s) * D;
    const float* xr1 = xr0 + D;

    float4 a0[12], a1[12];
#pragma unroll
    for (int j = 0; j < 12; ++j) {
        a0[j] = *reinterpret_cast<const float4*>(xr0 + j * 64 + ln * 4);
        a1[j] = *reinterpret_cast<const float4*>(xr1 + j * 64 + ln * 4);
    }
    float p0[16], p1[16];
#pragma unroll
    for (int n = 0; n < 16; ++n) {
        float q0 = 0.f, q1 = 0.f;
#pragma unroll
        for (int j = 0; j < 12; ++j) {
            const float4 pv = *reinterpret_cast<const float4*>(&ph[n][j * 64 + ln * 4]);
            q0 = fmaf(a0[j].x, pv.x, q0); q1 = fmaf(a1[j].x, pv.x, q1);
            q0 = fmaf(a0[j].y, pv.y, q0); q1 = fmaf(a1[j].y, pv.y, q1);
            q0 = fmaf(a0[j].z, pv.z, q0); q1 = fmaf(a1[j].z, pv.z, q1);
            q0 = fmaf(a0[j].w, pv.w, q0); q1 = fmaf(a1[j].w, pv.w, q1);
        }
        p0[n] = q0; p1[n] = q1;
    }
#pragma unroll
    for (int m = 1; m < 16; m <<= 1) {
#pragma unroll
        for (int n = 0; n < 16; ++n) {
            p0[n] += __shfl_xor(p0[n], m, 64);
            p1[n] += __shfl_xor(p1[n], m, 64);
        }
    }
    float m0 = -1e30f, m1 = -1e30f;
#pragma unroll
    for (int n = 0; n < 16; ++n) { m0 = fmaxf(m0, p0[n]); m1 = fmaxf(m1, p1[n]); }
    float su0 = 0.f, su1 = 0.f;
#pragma unroll
    for (int n = 0; n < 16; ++n) { su0 += __expf(p0[n] - m0); su1 += __expf(p1[n] - m1); }
    const size_t o0 = ((size_t)b * S + s) * N + ln;
    logits[o0] = p0[ln];
    logits[o0 + N] = p1[ln];
    dw[o0] = __expf(p0[ln] - m0) / su0;
    dw[o0 + N] = __expf(p1[ln] - m1) / su1;

    const float mm = fmaxf(p0[ln], p1[ln]);
    const float ss = __expf(p0[ln] - mm) + __expf(p1[ln] - mm);
    rm[gid][ln] = mm;
    rs[gid][ln] = ss;
    __syncthreads();
    if (t < 16) {
        float M = -1e30f;
#pragma unroll
        for (int g = 0; g < 16; ++g) M = fmaxf(M, rm[g][t]);
        float SS = 0.f;
#pragma unroll
        for (int g = 0; g < 16; ++g) SS += rs[g][t] * __expf(rm[g][t] - M);
        pcm[blk * 16 + t] = M;
        pcs[blk * 16 + t] = SS;
    }
}

// ---------------- K2: xs partials ----------------
// grid: B*NSCH = 512 blocks, 192 threads (thread owns 4 d via float4)
__global__ __launch_bounds__(192) void k_xsp(const float* __restrict__ x,
                                             const float* __restrict__ dw,
                                             float* __restrict__ xsp) {
    const int blk = blockIdx.x;
    const int b = blk / NSCH;
    const int c = blk % NSCH;
    const int t = threadIdx.x;
    const int d = t * 4;
    float4 a[16];
#pragma unroll
    for (int n = 0; n < 16; ++n) a[n] = float4{0.f, 0.f, 0.f, 0.f};
    const float* xb = x + ((size_t)b * S + (size_t)c * SCH) * D + d;
    const float* dwb = dw + ((size_t)b * S + (size_t)c * SCH) * N;
#pragma unroll 2
    for (int s = 0; s < SCH; ++s) {
        const float4 xv = *reinterpret_cast<const float4*>(xb + (size_t)s * D);
#pragma unroll
        for (int n = 0; n < 16; ++n) {
            const float w = dwb[s * N + n];
            a[n].x = fmaf(w, xv.x, a[n].x);
            a[n].y = fmaf(w, xv.y, a[n].y);
            a[n].z = fmaf(w, xv.z, a[n].z);
            a[n].w = fmaf(w, xv.w, a[n].w);
        }
    }
    float* o = xsp + (size_t)blk * N * D + d;
#pragma unroll
    for (int n = 0; n < 16; ++n)
        *reinterpret_cast<float4*>(o + (size_t)n * D) = a[n];
}

// ---------------- K3: reduce xs partials + merge combine stats ----------------
// grid: 193 blocks. 0..191: xsred (256 thr). 192: cmerge (t<64).
__global__ __launch_bounds__(256) void k_xsred_cmerge(const float* __restrict__ xsp,
                                                      float* __restrict__ xs,
                                                      const float* __restrict__ pcm,
                                                      const float* __restrict__ pcs,
                                                      float* __restrict__ cmax,
                                                      float* __restrict__ csum) {
    const int t = threadIdx.x;
    if (blockIdx.x < 192) {
        const int i = blockIdx.x * 256 + t;      // over B*N*D
        const int b = i / (N * D);
        const int rem = i % (N * D);
        const float* p = xsp + (size_t)b * NSCH * N * D + rem;
        float sum = 0.f;
#pragma unroll 4
        for (int c = 0; c < NSCH; ++c) sum += p[(size_t)c * N * D];
        xs[i] = sum;
    } else if (t < 64) {
        const int b = t >> 4, n = t & 15;
        float M = -1e30f;
#pragma unroll 8
        for (int c = 0; c < LPB; ++c) M = fmaxf(M, pcm[((size_t)b * LPB + c) * 16 + n]);
        float SS = 0.f;
#pragma unroll 8
        for (int c = 0; c < LPB; ++c)
            SS += pcs[((size_t)b * LPB + c) * 16 + n] * __expf(pcm[((size_t)b * LPB + c) * 16 + n] - M);
        cmax[b * 16 + n] = M;
        csum[b * 16 + n] = SS;
    }
}

// ---------------- K4: fused FFN (xs @ W1 -> GELU -> @ W2 partial) ----------------
// grid: E*NHC = 512 blocks, 384 threads. Block = (e, h-chunk of HL=96).
__global__ __launch_bounds__(384) void k_ffn(const float* __restrict__ xs,
                                             const float* __restrict__ W1,
                                             const float* __restrict__ b1,
                                             const float* __restrict__ W2,
                                             float* __restrict__ ysp) {
    __shared__ float xs_lds[D][4];          // [d][b] 12 KB
    __shared__ float4 red_lds[16][HL];      // phase-1 partials [q][col] 24 KB
    __shared__ float4 yq_lds[2][192][4];    // phase-2 partials 24 KB
    __shared__ float4 h_lds[HL];            // gelu(h) per col, 4 b's  1.5 KB

    const int t = threadIdx.x;
    const int e = blockIdx.x / NHC;
    const int hc = blockIdx.x % NHC;

    // phase 0: stage xs[:, e, :] transposed -> xs_lds[d][b]
    for (int idx = t; idx < D; idx += 384) {
#pragma unroll
        for (int b = 0; b < 4; ++b)
            xs_lds[idx][b] = xs[((size_t)b * N + e) * D + idx];
    }
    __syncthreads();

    // phase 1: h[b][col] = sum_d xs[b][d] * W1[e][d][hc*HL+col]
    {
        const int c4 = (t % 24) * 4;        // 4 cols
        const int q = t / 24;               // 0..15, d-range [q*48, q*48+48)
        float4 h0{0,0,0,0}, h1{0,0,0,0}, h2{0,0,0,0}, h3{0,0,0,0};  // per b, 4 cols
        const float* w1p = W1 + ((size_t)e * D + (size_t)q * 48) * H + hc * HL + c4;
#pragma unroll 8
        for (int dd = 0; dd < 48; ++dd) {
            const float4 w = *reinterpret_cast<const float4*>(w1p + (size_t)dd * H);
            const float* xv = &xs_lds[q * 48 + dd][0];
            const float x0 = xv[0], x1 = xv[1], x2 = xv[2], x3 = xv[3];
            h0.x = fmaf(x0, w.x, h0.x); h0.y = fmaf(x0, w.y, h0.y);
            h0.z = fmaf(x0, w.z, h0.z); h0.w = fmaf(x0, w.w, h0.w);
            h1.x = fmaf(x1, w.x, h1.x); h1.y = fmaf(x1, w.y, h1.y);
            h1.z = fmaf(x1, w.z, h1.z); h1.w = fmaf(x1, w.w, h1.w);
            h2.x = fmaf(x2, w.x, h2.x); h2.y = fmaf(x2, w.y, h2.y);
            h2.z = fmaf(x2, w.z, h2.z); h2.w = fmaf(x2, w.w, h2.w);
            h3.x = fmaf(x3, w.x, h3.x); h3.y = fmaf(x3, w.y, h3.y);
            h3.z = fmaf(x3, w.z, h3.z); h3.w = fmaf(x3, w.w, h3.w);
        }
        red_lds[q][c4 + 0] = float4{h0.x, h1.x, h2.x, h3.x};
        red_lds[q][c4 + 1] = float4{h0.y, h1.y, h2.y, h3.y};
        red_lds[q][c4 + 2] = float4{h0.z, h1.z, h2.z, h3.z};
        red_lds[q][c4 + 3] = float4{h0.w, h1.w, h2.w, h3.w};
    }
    __syncthreads();
    if (t < HL) {
        float4 s{0,0,0,0};
#pragma unroll
        for (int q = 0; q < 16; ++q) {
            const float4 v = red_lds[q][t];
            s.x += v.x; s.y += v.y; s.z += v.z; s.w += v.w;
        }
        const float bias = b1[(size_t)e * H + hc * HL + t];
        s.x += bias; s.y += bias; s.z += bias; s.w += bias;
        s.x = 0.5f * s.x * (1.0f + erff(s.x * 0.70710678118654752f));
        s.y = 0.5f * s.y * (1.0f + erff(s.y * 0.70710678118654752f));
        s.z = 0.5f * s.z * (1.0f + erff(s.z * 0.70710678118654752f));
        s.w = 0.5f * s.w * (1.0f + erff(s.w * 0.70710678118654752f));
        h_lds[t] = s;
    }
    __syncthreads();

    // phase 2: ysp_partial[b][d] = sum_{k in chunk} gelu_h[b][k] * W2[e][hc*HL+k][d]
    {
        const int dgrp = t % 192;
        const int d4 = dgrp * 4;
        const int kq = t / 192;             // 0/1, k-range [kq*48, kq*48+48)
        float4 y0{0,0,0,0}, y1{0,0,0,0}, y2{0,0,0,0}, y3{0,0,0,0};
        const float* w2p = W2 + ((size_t)e * H + hc * HL + kq * 48) * D + d4;
#pragma unroll 8
        for (int kk = 0; kk < 48; ++kk) {
            const float4 w = *reinterpret_cast<const float4*>(w2p + (size_t)kk * D);
            const float4 hv = h_lds[kq * 48 + kk];
            y0.x = fmaf(hv.x, w.x, y0.x); y0.y = fmaf(hv.x, w.y, y0.y);
            y0.z = fmaf(hv.x, w.z, y0.z); y0.w = fmaf(hv.x, w.w, y0.w);
            y1.x = fmaf(hv.y, w.x, y1.x); y1.y = fmaf(hv.y, w.y, y1.y);
            y1.z = fmaf(hv.y, w.z, y1.z); y1.w = fmaf(hv.y, w.w, y1.w);
            y2.x = fmaf(hv.z, w.x, y2.x); y2.y = fmaf(hv.z, w.y, y2.y);
            y2.z = fmaf(hv.z, w.z, y2.z); y2.w = fmaf(hv.z, w.w, y2.w);
            y3.x = fmaf(hv.w, w.x, y3.x); y3.y = fmaf(hv.w, w.y, y3.y);
            y3.z = fmaf(hv.w, w.z, y3.z); y3.w = fmaf(hv.w, w.w, y3.w);
        }
        yq_lds[kq][dgrp][0] = y0;
        yq_lds[kq][dgrp][1] = y1;
        yq_lds[kq][dgrp][2] = y2;
        yq_lds[kq][dgrp][3] = y3;
    }
    __syncthreads();
    if (t < 192) {
        const int d4 = t * 4;
#pragma unroll
        for (int b = 0; b < 4; ++b) {
            const float4 u = yq_lds[0][t][b];
            const float4 v = yq_lds[1][t][b];
            float4 r{u.x + v.x, u.y + v.y, u.z + v.z, u.w + v.w};
            *reinterpret_cast<float4*>(ysp + (((size_t)hc * B + b) * E + e) * D + d4) = r;
        }
    }
}

// ---------------- K5: reduce ys partials + b2 (float4) ----------------
// grid: B*E*D/4/256 = 48 blocks
__global__ __launch_bounds__(256) void k_ysred(const float* __restrict__ ysp,
                                               const float* __restrict__ b2,
                                               float* __restrict__ ys) {
    const int i4 = blockIdx.x * 256 + threadIdx.x;   // over B*E*D/4
    const int rem4 = i4 % (E * D / 4);
    float4 v = *reinterpret_cast<const float4*>(b2 + (size_t)rem4 * 4);
#pragma unroll 8
    for (int p = 0; p < NHC; ++p) {
        const float4 u = *reinterpret_cast<const float4*>(ysp + (size_t)p * B * E * D + (size_t)i4 * 4);
        v.x += u.x; v.y += u.y; v.z += u.z; v.w += u.w;
    }
    *reinterpret_cast<float4*>(ys + (size_t)i4 * 4) = v;
}

// ---------------- K6: combine ----------------
// grid: B*S/8 = 2048 blocks, 192 threads; block handles 8 s-rows; ys hoisted to regs
__global__ __launch_bounds__(192) void k_combine(const float* __restrict__ logits,
                                                 const float* __restrict__ cmax,
                                                 const float* __restrict__ csum,
                                                 const float* __restrict__ ys,
                                                 float* __restrict__ y) {
    const int blk = blockIdx.x;
    const int b = blk / (S / 8);
    const int s0 = (blk % (S / 8)) * 8;
    const int t = threadIdx.x;
    const int d4 = t * 4;

    float4 ysr[16];
    float cm[16], ci[16];
#pragma unroll
    for (int n = 0; n < 16; ++n) {
        ysr[n] = *reinterpret_cast<const float4*>(ys + ((size_t)b * N + n) * D + d4);
        cm[n] = cmax[b * N + n];
        ci[n] = 1.0f / csum[b * N + n];
    }
#pragma unroll
    for (int r = 0; r < 8; ++r) {
        const int s = s0 + r;
        const float* lrow = logits + ((size_t)b * S + s) * N;
        float4 acc{0,0,0,0};
#pragma unroll
        for (int n = 0; n < 16; ++n) {
            const float cw = __expf(lrow[n] - cm[n]) * ci[n];
            acc.x = fmaf(cw, ysr[n].x, acc.x);
            acc.y = fmaf(cw, ysr[n].y, acc.y);
            acc.z = fmaf(cw, ysr[n].z, acc.z);
            acc.w = fmaf(cw, ysr[n].w, acc.w);
        }
        *reinterpret_cast<float4*>(y + ((size_t)b * S + s) * D + d4) = acc;
    }
}

extern "C" void kernel_launch(void* const* d_in, const int* in_sizes, int n_in,
                              void* d_out, int out_size, void* d_ws, size_t ws_size,
                              hipStream_t stream) {
    const float* x   = (const float*)d_in[0];
    const float* phi = (const float*)d_in[1];
    const float* W1  = (const float*)d_in[2];
    const float* b1  = (const float*)d_in[3];
    const float* W2  = (const float*)d_in[4];
    const float* b2  = (const float*)d_in[5];
    float* y = (float*)d_out;
    float* ws = (float*)d_ws;

    float* logits = ws + OFF_LOG;
    float* dw     = ws + OFF_DW;
    float* pcm    = ws + OFF_PCM;
    float* pcs    = ws + OFF_PCS;
    float* cmax   = ws + OFF_CMAX;
    float* csum   = ws + OFF_CSUM;
    float* xsp    = ws + OFF_XSP;
    float* xs     = ws + OFF_XS;
    float* ysp    = ws + OFF_YSP;
    float* ys     = ws + OFF_YS;

    k_logits<<<B * LPB, 256, 0, stream>>>(x, phi, logits, dw, pcm, pcs);
    k_xsp<<<B * NSCH, 192, 0, stream>>>(x, dw, xsp);
    k_xsred_cmerge<<<193, 256, 0, stream>>>(xsp, xs, pcm, pcs, cmax, csum);
    k_ffn<<<E * NHC, 384, 0, stream>>>(xs, W1, b1, W2, ysp);
    k_ysred<<<48, 256, 0, stream>>>(ysp, b2, ys);
    k_combine<<<B * (S / 8), 192, 0, stream>>>(logits, cmax, csum, ys, y);
}